// Round 2
// baseline (134.233 us; speedup 1.0000x reference)
//
#include <hip/hip_runtime.h>

// StatefulLIF: x [B,T,N] f32, membrane [B,N], trace [B,N]
// out = concat(spikes [B,T,N], m_f [B,N], tr_f [B,N]) as f32.
// Recurrence sequential in T; B*N = 16384 independent chains
// = 256 CUs x 64 lanes x 1 wave exactly -> latency-bound, 1 wave/CU.
// Strategy: 1 thread per chain, lane-contiguous n (coalesced 256B/wave),
// explicit 2-buffer x-prefetch pipeline at U=64 so prefetch->use distance
// covers ~768cy of compute (~ HBM miss latency ~900cy, m126).

#define LIF_B 8
#define LIF_T 1024
#define LIF_N 2048

// float(exp(-1/10)), float(exp(-1/5)) — same f64->f32 rounding as jnp.asarray
#define A_MEM 0.90483741803595952f
#define A_SYN 0.81873075307798185f

__global__ __launch_bounds__(64) void lif_seq_kernel(
    const float* __restrict__ x,
    const float* __restrict__ m0,
    const float* __restrict__ tr0,
    float* __restrict__ out) {
  const int chain = blockIdx.x * 64 + threadIdx.x;  // 0..16383
  const int b = chain >> 11;            // / N
  const int n = chain & (LIF_N - 1);    // % N

  const size_t plane = (size_t)LIF_T * LIF_N;
  const float* __restrict__ xp = x + (size_t)b * plane + n;
  float* __restrict__ sp = out + (size_t)b * plane + n;

  float m  = m0[chain];
  float tr = tr0[chain];

  constexpr float am   = A_MEM;
  constexpr float as   = A_SYN;
  constexpr float onem = 1.0f - A_MEM;  // exact f32, matches reference (1 - a_m)

  constexpr int U = 64;                 // per-buffer depth
  float xa[U], xb[U];

  // prologue: fill both buffers (batches 0 and 1)
  #pragma unroll
  for (int j = 0; j < U; ++j) xa[j] = xp[(size_t)j * LIF_N];
  #pragma unroll
  for (int j = 0; j < U; ++j) xb[j] = xp[(size_t)(U + j) * LIF_N];

  // one LIF step; store spike nontemporally (write-once stream)
  #define LIF_STEP(xv, tt)                                             \
    do {                                                               \
      m = fmaf(am, m, onem * (xv));                                    \
      float s_ = (m > 1.0f) ? 1.0f : 0.0f; /* V_TH = 1 */              \
      m -= s_;                             /* reset_amt = 1 */         \
      tr = fmaf(as, tr, s_);                                           \
      __builtin_nontemporal_store(s_, &sp[(size_t)(tt) * LIF_N]);      \
    } while (0)

  #pragma unroll 1
  for (int t = 0; t < LIF_T; t += 2 * U) {  // 8 iterations
    // compute batch t (buffer A) — its loads were issued 2 batches ago
    #pragma unroll
    for (int j = 0; j < U; ++j) LIF_STEP(xa[j], t + j);
    // refill A with batch t+2U
    if (t + 2 * U < LIF_T) {
      #pragma unroll
      for (int j = 0; j < U; ++j) xa[j] = xp[(size_t)(t + 2 * U + j) * LIF_N];
    }
    // compute batch t+U (buffer B) — covers A's refill latency (~768cy)
    #pragma unroll
    for (int j = 0; j < U; ++j) LIF_STEP(xb[j], t + U + j);
    // refill B with batch t+3U
    if (t + 3 * U < LIF_T) {
      #pragma unroll
      for (int j = 0; j < U; ++j) xb[j] = xp[(size_t)(t + 3 * U + j) * LIF_N];
    }
  }
  #undef LIF_STEP

  float* mf  = out + (size_t)LIF_B * plane;       // final membrane [B,N]
  float* trf = mf + (size_t)LIF_B * LIF_N;        // final trace [B,N]
  mf[chain]  = m;
  trf[chain] = tr;
}

extern "C" void kernel_launch(void* const* d_in, const int* in_sizes, int n_in,
                              void* d_out, int out_size, void* d_ws, size_t ws_size,
                              hipStream_t stream) {
  const float* x   = (const float*)d_in[0];
  const float* m0  = (const float*)d_in[1];
  const float* tr0 = (const float*)d_in[2];
  float* out = (float*)d_out;

  const int chains = LIF_B * LIF_N;  // 16384
  const int block = 64;
  const int grid = chains / block;   // 256 blocks -> 1 block (1 wave) per CU
  lif_seq_kernel<<<grid, block, 0, stream>>>(x, m0, tr0, out);
}

// Round 6
// 123.714 us; speedup vs baseline: 1.0850x; 1.0850x over previous
//
#include <hip/hip_runtime.h>

// StatefulLIF producer/consumer: x [B,T,N] f32 -> spikes [B,T,N] + m_f + tr_f.
// B*N = 16384 chains = 256 blocks x 64 lanes. Per block: wave0 = loader
// (global_load_lds x-chunks into LDS double buffer), wave1 = compute
// (ds_read x, serial LIF chain, nontemporal global spike stores).
// Rationale: compute wave's vmcnt holds ONLY stores -> never waited on
// (r2 showed load/store vmcnt entanglement serialized the chain at
// ~120cy/step). Raw s_barrier (not __syncthreads) so stores stay in flight
// across chunk boundaries.

#define LIF_B 8
#define LIF_T 1024
#define LIF_N 2048

// float(exp(-1/10)), float(exp(-1/5))
#define A_MEM 0.90483741803595952f
#define A_SYN 0.81873075307798185f

#define CHUNK 64
#define NCHUNK (LIF_T / CHUNK)   // 16

// compiler-level fence + hw barrier; s_barrier intrinsic alone is IntrNoMem,
// the "memory" asm clobbers pin LDS op ordering at source level.
#define BARRIER()                                  \
  do {                                             \
    __asm__ __volatile__("" ::: "memory");         \
    __builtin_amdgcn_s_barrier();                  \
    __asm__ __volatile__("" ::: "memory");         \
  } while (0)

__global__ __launch_bounds__(128) void lif_pc_kernel(
    const float* __restrict__ x,
    const float* __restrict__ m0,
    const float* __restrict__ tr0,
    float* __restrict__ out) {
  // [buf][step][lane] — global_load_lds writes wave-uniform base + lane*4,
  // so inner dim must be the 64 lanes, contiguous, unpadded (rule #21).
  __shared__ float xbuf[2][CHUNK][64];

  const int wid = threadIdx.x >> 6;     // 0 = loader, 1 = compute
  const int l   = threadIdx.x & 63;
  const int chain = blockIdx.x * 64 + l;        // 0..16383
  const int b = chain >> 11;                    // / N
  const int n = chain & (LIF_N - 1);            // % N
  const size_t plane = (size_t)LIF_T * LIF_N;
  const float* __restrict__ xp = x + (size_t)b * plane + n;

  if (wid == 0) {
    // loader prologue: DMA chunk 0 into buf 0
    #pragma unroll
    for (int j = 0; j < CHUNK; ++j) {
      __builtin_amdgcn_global_load_lds(
          (const __attribute__((address_space(1))) void*)(xp + (size_t)j * LIF_N),
          (__attribute__((address_space(3))) void*)(&xbuf[0][j][0]),
          4, 0, 0);
    }
    __asm__ __volatile__("s_waitcnt vmcnt(0)" ::: "memory");
  }

  float m = 0.f, tr = 0.f;
  float* sp = nullptr;
  if (wid == 1) {
    m  = m0[chain];
    tr = tr0[chain];
    sp = out + (size_t)b * plane + n;
  }

  BARRIER();  // chunk 0 visible to compute

  constexpr float am   = A_MEM;
  constexpr float as   = A_SYN;
  constexpr float onem = 1.0f - A_MEM;  // matches reference (1 - a_m) in f32

  #pragma unroll 1
  for (int c = 0; c < NCHUNK; ++c) {
    if (wid == 0) {
      // prefetch chunk c+1 into the other buffer while compute eats chunk c
      if (c + 1 < NCHUNK) {
        const float* g = xp + (size_t)(c + 1) * CHUNK * LIF_N;
        #pragma unroll
        for (int j = 0; j < CHUNK; ++j) {
          __builtin_amdgcn_global_load_lds(
              (const __attribute__((address_space(1))) void*)(g + (size_t)j * LIF_N),
              (__attribute__((address_space(3))) void*)(&xbuf[(c + 1) & 1][j][0]),
              4, 0, 0);
        }
      }
      // loads must be IN LDS before the barrier releases compute
      __asm__ __volatile__("s_waitcnt vmcnt(0)" ::: "memory");
    } else {
      // consume chunk c: LDS -> regs (lgkmcnt path, conflict-free: lane=bank)
      float xr[CHUNK];
      #pragma unroll
      for (int j = 0; j < CHUNK; ++j) xr[j] = xbuf[c & 1][j][l];
      float* spc = sp + (size_t)c * CHUNK * LIF_N;
      #pragma unroll
      for (int j = 0; j < CHUNK; ++j) {
        m = fmaf(am, m, onem * xr[j]);
        float s_ = (m > 1.0f) ? 1.0f : 0.0f;  // V_TH = 1
        m -= s_;                              // reset_amt = 1
        tr = fmaf(as, tr, s_);
        __builtin_nontemporal_store(s_, spc + (size_t)j * LIF_N);
      }
    }
    BARRIER();  // buf(c&1) free for reuse; buf((c+1)&1) ready
  }

  if (wid == 1) {
    float* mf  = out + (size_t)LIF_B * plane;   // final membrane [B,N]
    float* trf = mf + (size_t)LIF_B * LIF_N;    // final trace [B,N]
    mf[chain]  = m;
    trf[chain] = tr;
  }
}

extern "C" void kernel_launch(void* const* d_in, const int* in_sizes, int n_in,
                              void* d_out, int out_size, void* d_ws, size_t ws_size,
                              hipStream_t stream) {
  const float* x   = (const float*)d_in[0];
  const float* m0  = (const float*)d_in[1];
  const float* tr0 = (const float*)d_in[2];
  float* out = (float*)d_out;

  const int grid = (LIF_B * LIF_N) / 64;  // 256 blocks -> 1 per CU
  lif_pc_kernel<<<grid, 128, 0, stream>>>(x, m0, tr0, out);
}

// Round 8
// 123.405 us; speedup vs baseline: 1.0877x; 1.0025x over previous
//
#include <hip/hip_runtime.h>

// StatefulLIF r7: wave-specialized producer/consumer with 4-deep LDS ring.
// x [B,T,N] f32 -> out = concat(spikes [B,T,N], m_f [B,N], tr_f [B,N]).
// 16384 chains = 256 blocks x 64 lanes, 1 block/CU, 2 waves/block:
//   wave0 loader: global_load_lds dwordx4 (4 timesteps/instr), ring of 4
//                 chunk buffers, counted vmcnt waits (prefetch depth 3).
//   wave1 compute: ds_read x (lgkmcnt), serial LIF chain, nontemporal
//                  spike stores (vmcnt holds ONLY stores -> never waited).
// r2 counters showed load/store vmcnt entanglement serialized the chain
// (~120cy/step); r6 (depth-1, vmcnt(0)/chunk) got to ~40us; this deepens
// the pipeline so HBM latency under load (~2-3Kcy) is covered.

#define LIF_B 8
#define LIF_T 1024
#define LIF_N 2048

// float(exp(-1/10)), float(exp(-1/5))
#define A_MEM 0.90483741803595952f
#define A_SYN 0.81873075307798185f

#define CHUNK 64
#define NCHUNK (LIF_T / CHUNK)        // 16
#define NBUF 4                        // ring depth; 4*64*256B = 64KB LDS
#define LPC 16                        // loads/chunk: dwordx4 covers 4 steps

#define BARRIER()                                  \
  do {                                             \
    __asm__ __volatile__("" ::: "memory");         \
    __builtin_amdgcn_s_barrier();                  \
    __asm__ __volatile__("" ::: "memory");         \
  } while (0)

#define WAITV(n) __asm__ __volatile__("s_waitcnt vmcnt(" #n ")" ::: "memory")

__global__ __launch_bounds__(128) void lif_pc_kernel(
    const float* __restrict__ x,
    const float* __restrict__ m0,
    const float* __restrict__ tr0,
    float* __restrict__ out) {
  // [buf][step][lane]: global_load_lds size=16 writes lane l's 16B at
  // byte 16*l => step row l>>4, floats 4*(l&15).. (256B per step row).
  __shared__ float xbuf[NBUF][CHUNK][64];

  const int wid = threadIdx.x >> 6;   // 0 = loader, 1 = compute
  const int l   = threadIdx.x & 63;
  const int b   = blockIdx.x >> 5;                  // 32 blocks per batch
  const int n0  = (blockIdx.x * 64) & (LIF_N - 1);  // block's chain base
  const size_t plane = (size_t)LIF_T * LIF_N;

  // loader lane l sources step-row (l>>4), chains n0+4*(l&15)..+3
  const float* __restrict__ gl =
      x + (size_t)b * plane + (size_t)(l >> 4) * LIF_N + n0 + 4 * (l & 15);

  // one chunk = 16 dwordx4 global_load_lds, 4 timesteps each
  #define ISSUE_CHUNK(cc)                                                    \
    do {                                                                     \
      const float* g_ = gl + (size_t)(cc) * CHUNK * LIF_N;                   \
      float(*lb_)[64] = xbuf[(cc) & (NBUF - 1)];                             \
      _Pragma("unroll")                                                      \
      for (int i_ = 0; i_ < LPC; ++i_) {                                     \
        __builtin_amdgcn_global_load_lds(                                    \
            (const __attribute__((address_space(1))) void*)(                 \
                g_ + (size_t)(4 * i_) * LIF_N),                              \
            (__attribute__((address_space(3))) void*)(&lb_[4 * i_][0]),      \
            16, 0, 0);                                                       \
      }                                                                      \
    } while (0)

  float m = 0.f, tr = 0.f;
  float* sp = nullptr;
  if (wid == 0) {
    // prologue: chunks 0,1,2 in flight (48 vmem), chunk 0 must land
    ISSUE_CHUNK(0);
    ISSUE_CHUNK(1);
    ISSUE_CHUNK(2);
    WAITV(32);                        // chunk 0 complete; 1,2 in flight
  } else {
    const int chain = blockIdx.x * 64 + l;
    m  = m0[chain];
    tr = tr0[chain];
    sp = out + (size_t)b * plane + n0 + l;
  }

  BARRIER();                          // chunk 0 visible

  constexpr float am   = A_MEM;
  constexpr float as   = A_SYN;
  constexpr float onem = 1.0f - A_MEM;  // matches reference (1 - a_m) in f32

  #pragma unroll 1
  for (int c = 0; c < NCHUNK; ++c) {
    if (wid == 0) {
      // invariant at iter c entry: chunks c+1,c+2 outstanding (32 vmem)
      if (c + 3 < NCHUNK) {
        ISSUE_CHUNK(c + 3);           // -> c+1,c+2,c+3 (48)
        WAITV(32);                    // chunk c+1 landed (in-order retire)
      } else if (c == NCHUNK - 3) {
        WAITV(16);                    // chunk c+1 landed, c+2 in flight
      } else if (c == NCHUNK - 2) {
        WAITV(0);                     // last chunk landed
      }                               // c == NCHUNK-1: nothing to wait
    } else {
      float xr[CHUNK];
      float(*lb)[64] = xbuf[c & (NBUF - 1)];
      #pragma unroll
      for (int j = 0; j < CHUNK; ++j) xr[j] = lb[j][l];  // bank l%32, 2-way: free
      float* spc = sp + (size_t)c * CHUNK * LIF_N;
      #pragma unroll
      for (int j = 0; j < CHUNK; ++j) {
        m = fmaf(am, m, onem * xr[j]);
        float s_ = (m > 1.0f) ? 1.0f : 0.0f;  // V_TH = 1
        m -= s_;                              // reset_amt = 1
        tr = fmaf(as, tr, s_);
        __builtin_nontemporal_store(s_, spc + (size_t)j * LIF_N);
      }
    }
    // loader may overwrite buf (c+4)&3 == (c)&3 only after NEXT barrier;
    // write target (c+3)&3 != read target c&3 -> one barrier/iter suffices
    BARRIER();
  }
  #undef ISSUE_CHUNK

  if (wid == 1) {
    const int chain = blockIdx.x * 64 + l;
    float* mf  = out + (size_t)LIF_B * plane;   // final membrane [B,N]
    float* trf = mf + (size_t)LIF_B * LIF_N;    // final trace [B,N]
    mf[chain]  = m;
    trf[chain] = tr;
  }
}

extern "C" void kernel_launch(void* const* d_in, const int* in_sizes, int n_in,
                              void* d_out, int out_size, void* d_ws, size_t ws_size,
                              hipStream_t stream) {
  const float* x   = (const float*)d_in[0];
  const float* m0  = (const float*)d_in[1];
  const float* tr0 = (const float*)d_in[2];
  float* out = (float*)d_out;

  const int grid = (LIF_B * LIF_N) / 64;  // 256 blocks -> 1 per CU
  lif_pc_kernel<<<grid, 128, 0, stream>>>(x, m0, tr0, out);
}

// Round 11
// 120.432 us; speedup vs baseline: 1.1146x; 1.0247x over previous
//
#include <hip/hip_runtime.h>

// StatefulLIF r11 (= r9 + compile fix): 3-way wave specialization.
//   wave0 loader : global_load_lds dwordx4, 4-deep x-ring, counted vmcnt.
//   wave1 compute: VMEM-FREE steady state — ds_read x, serial LIF chain,
//                  ds_write spikes into 2-deep LDS spike ring.
//   wave2+3 store: ds_read_b128 spike ring -> nontemporal dwordx4 stores
//                  (1KB/instr; 2x63 outstanding = >100KB in flight/CU).
// r8 showed load depth/width neutral at ~40us (~94cy/step): compute wave was
// throttled by its own scalar-store queue (63 x 256B in flight). This moves
// ALL global stores off the compute wave and widens them 4x.
// r10 fix: __builtin_nontemporal_store needs a clang ext_vector_type, not
// HIP's float4 class -> use f32x4.

#define LIF_B 8
#define LIF_T 1024
#define LIF_N 2048

// float(exp(-1/10)), float(exp(-1/5))
#define A_MEM 0.90483741803595952f
#define A_SYN 0.81873075307798185f

#define CHUNK 64
#define NCHUNK (LIF_T / CHUNK)        // 16
#define NXBUF 4                       // x ring: 4*16KB = 64KB
#define NSBUF 2                       // spike ring: 2*16KB = 32KB
#define LPC 16                        // x-loads/chunk (dwordx4 = 4 steps each)

typedef float f32x4 __attribute__((ext_vector_type(4)));

#define BARRIER()                                  \
  do {                                             \
    __asm__ __volatile__("" ::: "memory");         \
    __builtin_amdgcn_s_barrier();                  \
    __asm__ __volatile__("" ::: "memory");         \
  } while (0)

#define WAITV(n) __asm__ __volatile__("s_waitcnt vmcnt(" #n ")" ::: "memory")
#define WAITL0() __asm__ __volatile__("s_waitcnt lgkmcnt(0)" ::: "memory")

__global__ __launch_bounds__(256) void lif_pc_kernel(
    const float* __restrict__ x,
    const float* __restrict__ m0,
    const float* __restrict__ tr0,
    float* __restrict__ out) {
  // [buf][step][lane]; global_load_lds size=16: lane l -> byte 16l = row l>>4,
  // floats 4*(l&15).. ; matches source row (l>>4), col n0+4*(l&15).
  __shared__ float xbuf[NXBUF][CHUNK][64];   // 64 KB
  __shared__ float sbuf[NSBUF][CHUNK][64];   // 32 KB

  const int wid = threadIdx.x >> 6;   // 0 loader, 1 compute, 2/3 storers
  const int l   = threadIdx.x & 63;
  const int b   = blockIdx.x >> 5;                  // 32 blocks per batch
  const int n0  = (blockIdx.x * 64) & (LIF_N - 1);  // block's chain base
  const size_t plane = (size_t)LIF_T * LIF_N;

  // loader lane l sources step-row (l>>4), chains n0+4*(l&15)..+3
  const float* __restrict__ gl =
      x + (size_t)b * plane + (size_t)(l >> 4) * LIF_N + n0 + 4 * (l & 15);

  #define ISSUE_CHUNK(cc)                                                    \
    do {                                                                     \
      const float* g_ = gl + (size_t)(cc) * CHUNK * LIF_N;                   \
      float(*lb_)[64] = xbuf[(cc) & (NXBUF - 1)];                            \
      _Pragma("unroll")                                                      \
      for (int i_ = 0; i_ < LPC; ++i_) {                                     \
        __builtin_amdgcn_global_load_lds(                                    \
            (const __attribute__((address_space(1))) void*)(                 \
                g_ + (size_t)(4 * i_) * LIF_N),                              \
            (__attribute__((address_space(3))) void*)(&lb_[4 * i_][0]),      \
            16, 0, 0);                                                       \
      }                                                                      \
    } while (0)

  float m = 0.f, tr = 0.f;
  if (wid == 0) {
    ISSUE_CHUNK(0);
    ISSUE_CHUNK(1);
    ISSUE_CHUNK(2);
    WAITV(32);                        // chunk 0 landed; 1,2 in flight
  } else if (wid == 1) {
    const int chain = blockIdx.x * 64 + l;
    m  = m0[chain];
    tr = tr0[chain];
  }

  BARRIER();                          // chunk 0 visible

  constexpr float am   = A_MEM;
  constexpr float as   = A_SYN;
  constexpr float onem = 1.0f - A_MEM;  // matches reference (1 - a_m) in f32

  #pragma unroll 1
  for (int c = 0; c <= NCHUNK; ++c) {
    if (wid == 0) {
      // entering iter c (c<NCHUNK): chunks c+1,c+2 outstanding (32 vmem)
      if (c + 3 < NCHUNK) {
        ISSUE_CHUNK(c + 3);           // -> 48 outstanding
        WAITV(32);                    // chunk c+1 landed (in-order retire)
      } else if (c == NCHUNK - 3) {
        WAITV(16);
      } else if (c == NCHUNK - 2) {
        WAITV(0);
      }
    } else if (wid == 1) {
      if (c < NCHUNK) {
        float xr[CHUNK];
        float(*lb)[64] = xbuf[c & (NXBUF - 1)];
        #pragma unroll
        for (int j = 0; j < CHUNK; ++j) xr[j] = lb[j][l];  // 2-way bank: free
        float(*sb)[64] = sbuf[c & (NSBUF - 1)];
        #pragma unroll
        for (int j = 0; j < CHUNK; ++j) {
          m = fmaf(am, m, onem * xr[j]);
          float md = m - 1.0f;                 // off-chain with cmp
          bool  gt = (m > 1.0f);               // V_TH = 1
          float s_ = gt ? 1.0f : 0.0f;
          m = gt ? md : m;                     // reset_amt = 1
          tr = fmaf(as, tr, s_);
          sb[j][l] = s_;                       // ds_write, 2-way bank: free
        }
        WAITL0();                              // spikes visible pre-barrier
      }
    } else {
      if (c >= 1) {
        // store chunk c-1 from sbuf[(c-1)&1]; storer w2 owns steps 32w2..+31
        const int w2 = wid - 2;
        float(*sb)[64] = sbuf[(c - 1) & (NSBUF - 1)];
        float* g = out + (size_t)b * plane +
                   ((size_t)(c - 1) * CHUNK + 32 * w2 + (l >> 4)) * LIF_N +
                   n0 + 4 * (l & 15);
        f32x4 v[8];
        #pragma unroll
        for (int i = 0; i < 8; ++i) {
          const float* src = &sb[32 * w2 + 4 * i + (l >> 4)][4 * (l & 15)];
          v[i] = *reinterpret_cast<const f32x4*>(src);    // ds_read_b128
        }
        #pragma unroll
        for (int i = 0; i < 8; ++i) {
          __builtin_nontemporal_store(
              v[i], reinterpret_cast<f32x4*>(g + (size_t)(4 * i) * LIF_N));
        }
      }
    }
    // ring safety: x write target (c+3)&3 != read c&3; spike write c&1 !=
    // storer read (c-1)&1; storer ds_reads retire before it passes barrier.
    BARRIER();
  }
  #undef ISSUE_CHUNK

  if (wid == 1) {
    const int chain = blockIdx.x * 64 + l;
    float* mf  = out + (size_t)LIF_B * plane;   // final membrane [B,N]
    float* trf = mf + (size_t)LIF_B * LIF_N;    // final trace [B,N]
    mf[chain]  = m;
    trf[chain] = tr;
  }
}

extern "C" void kernel_launch(void* const* d_in, const int* in_sizes, int n_in,
                              void* d_out, int out_size, void* d_ws, size_t ws_size,
                              hipStream_t stream) {
  const float* x   = (const float*)d_in[0];
  const float* m0  = (const float*)d_in[1];
  const float* tr0 = (const float*)d_in[2];
  float* out = (float*)d_out;

  const int grid = (LIF_B * LIF_N) / 64;  // 256 blocks -> 1 per CU
  lif_pc_kernel<<<grid, 256, 0, stream>>>(x, m0, tr0, out);
}